// Round 4
// baseline (165.837 us; speedup 1.0000x reference)
//
#include <hip/hip_runtime.h>
#include <hip/hip_bf16.h>

// Problem constants (from reference)
#define BATCH   16
#define OUT_C   256
#define KK      3
#define Z_DIM   64
#define H_DIM   128
#define W_DIM   128

typedef float vf4 __attribute__((ext_vector_type(4)));   // clang-native vec4

// ---------------------------------------------------------------------------
// Kernel 1: W_dw[b, j] = dot(z[b, :], W_lin[j, :])   j in [0, OUT_C*K*K)
// Tiny: 36,864 outputs x 64 MACs. float4-vectorized.
// ---------------------------------------------------------------------------
__global__ void hyper_gemm_kernel(const float* __restrict__ z,
                                  const float* __restrict__ W_lin,
                                  float* __restrict__ wdw) {
    const int tid = blockIdx.x * blockDim.x + threadIdx.x;
    const int total = BATCH * OUT_C * KK * KK;   // 36864
    if (tid >= total) return;
    const int b = tid / (OUT_C * KK * KK);
    const int j = tid - b * (OUT_C * KK * KK);

    const vf4* zr = reinterpret_cast<const vf4*>(z + b * Z_DIM);
    const vf4* wr = reinterpret_cast<const vf4*>(W_lin + (size_t)j * Z_DIM);

    float acc = 0.f;
#pragma unroll
    for (int i = 0; i < Z_DIM / 4; ++i) {
        vf4 a = zr[i];
        vf4 w = wr[i];
        acc += a.x * w.x + a.y * w.y + a.z * w.z + a.w * w.w;
    }
    wdw[tid] = acc;
}

// ---------------------------------------------------------------------------
// Kernel 2: depthwise 3x3 conv, pad 1, per-sample weights.
//
// One block per (b,c) plane. 256 threads = 16 col-groups x 16 row-groups.
//   tcol = tid & 15  -> 8 consecutive cols  (16*8 = 128 = W)
//   trow = tid >> 4  -> 8 consecutive rows  (16*8 = 128 = H)
//
// All 10 input rows (8 outputs + 2 halo rows) are loaded UPFRONT as 20
// coalesced dwordx4 (branchless: clamped row address + cndmask zero for
// out-of-plane rows) -> 20 outstanding loads per wave for max MLP.
// Column halos come from neighbor lanes via __shfl_up/__shfl_down (lane i-1
// holds col c0-1 as its m1.w, lane i+1 holds col c0+8 as its m0.x), so there
// are ZERO scalar/uncoalesced global loads.
// ---------------------------------------------------------------------------
__global__ __launch_bounds__(256)
void dwconv3x3_kernel(const float* __restrict__ x,
                      const float* __restrict__ wdw,
                      float* __restrict__ out) {
    const int plane = blockIdx.x;                                  // b*OUT_C + c

    const float* __restrict__ xin  = x   + (size_t)plane * (H_DIM * W_DIM);
    float*       __restrict__ oout = out + (size_t)plane * (H_DIM * W_DIM);

    // 9 per-plane weights — uniform address, scalar (SGPR) loads.
    const float* __restrict__ wp = wdw + (size_t)plane * (KK * KK);
    const float w00 = wp[0], w01 = wp[1], w02 = wp[2];
    const float w10 = wp[3], w11 = wp[4], w12 = wp[5];
    const float w20 = wp[6], w21 = wp[7], w22 = wp[8];

    const int tcol = threadIdx.x & 15;
    const int trow = threadIdx.x >> 4;
    const int c0   = tcol * 8;          // 0..120
    const int r0   = trow * 8;          // 0..120

    // ---- phase 1: issue all 20 coalesced loads (10 rows x 2 dwordx4) ----
    vf4 m0[10], m1[10];
#pragma unroll
    for (int i = 0; i < 10; ++i) {
        const int ir  = r0 - 1 + i;                    // r0-1 .. r0+8
        const int irc = ir < 0 ? 0 : (ir > H_DIM - 1 ? H_DIM - 1 : ir);
        const float* p = xin + irc * W_DIM + c0;
        vf4 a = *reinterpret_cast<const vf4*>(p);
        vf4 b = *reinterpret_cast<const vf4*>(p + 4);
        const bool inb = (ir >= 0) && (ir < H_DIM);
        const float msk = inb ? 1.f : 0.f;             // v_cndmask, no branch
        m0[i] = a * msk;
        m1[i] = b * msk;
    }

    // ---- phase 2: column halos via cross-lane shuffle (no divergence) ----
    float lft[10], rgt[10];
#pragma unroll
    for (int i = 0; i < 10; ++i) {
        const float tl = __shfl_up(m1[i].w, 1);        // lane i-1's col c0-1
        const float tr = __shfl_down(m0[i].x, 1);      // lane i+1's col c0+8
        lft[i] = (tcol == 0)  ? 0.f : tl;
        rgt[i] = (tcol == 15) ? 0.f : tr;
    }

    // ---- phase 3: 8 output rows, 9 FMA per output, dwordx4 stores ----
#pragma unroll
    for (int j = 0; j < 8; ++j) {
        const int iA = j, iB = j + 1, iC = j + 2;

        const float A[10] = { lft[iA], m0[iA].x, m0[iA].y, m0[iA].z, m0[iA].w,
                              m1[iA].x, m1[iA].y, m1[iA].z, m1[iA].w, rgt[iA] };
        const float Bv[10] = { lft[iB], m0[iB].x, m0[iB].y, m0[iB].z, m0[iB].w,
                               m1[iB].x, m1[iB].y, m1[iB].z, m1[iB].w, rgt[iB] };
        const float Cv[10] = { lft[iC], m0[iC].x, m0[iC].y, m0[iC].z, m0[iC].w,
                               m1[iC].x, m1[iC].y, m1[iC].z, m1[iC].w, rgt[iC] };

        float o[8];
#pragma unroll
        for (int k = 0; k < 8; ++k) {
            float a;
            a = fmaf(w00, A[k],  fmaf(w01, A[k + 1],  w02 * A[k + 2]));
            a = fmaf(w10, Bv[k], fmaf(w11, Bv[k + 1], fmaf(w12, Bv[k + 2], a)));
            a = fmaf(w20, Cv[k], fmaf(w21, Cv[k + 1], fmaf(w22, Cv[k + 2], a)));
            o[k] = a;
        }

        vf4 s0, s1;
        s0.x = o[0]; s0.y = o[1]; s0.z = o[2]; s0.w = o[3];
        s1.x = o[4]; s1.y = o[5]; s1.z = o[6]; s1.w = o[7];
        float* op = oout + (r0 + j) * W_DIM + c0;
        __builtin_nontemporal_store(s0, reinterpret_cast<vf4*>(op));
        __builtin_nontemporal_store(s1, reinterpret_cast<vf4*>(op + 4));
    }
}

// ---------------------------------------------------------------------------
extern "C" void kernel_launch(void* const* d_in, const int* in_sizes, int n_in,
                              void* d_out, int out_size, void* d_ws, size_t ws_size,
                              hipStream_t stream) {
    const float* x     = (const float*)d_in[0];   // (B, C, H, W)
    const float* z     = (const float*)d_in[1];   // (B, Z)
    const float* W_lin = (const float*)d_in[2];   // (C*K*K, Z)
    float* out = (float*)d_out;
    float* wdw = (float*)d_ws;                    // (B, C*K*K) = 36864 floats

    // Stage 1: hypernetwork weights
    {
        const int total = BATCH * OUT_C * KK * KK;  // 36864
        const int blk = 256;
        hyper_gemm_kernel<<<(total + blk - 1) / blk, blk, 0, stream>>>(z, W_lin, wdw);
    }

    // Stage 2: depthwise conv — one block per (b,c) plane
    {
        const int grid = BATCH * OUT_C;             // 4096
        dwconv3x3_kernel<<<grid, 256, 0, stream>>>(x, wdw, out);
    }
}

// Round 5
// 102.157 us; speedup vs baseline: 1.6234x; 1.6234x over previous
//
#include <hip/hip_runtime.h>
#include <hip/hip_bf16.h>

// Problem constants (from reference)
#define BATCH   16
#define OUT_C   256
#define KK      3
#define Z_DIM   64
#define H_DIM   128
#define W_DIM   128

typedef float vf4 __attribute__((ext_vector_type(4)));   // clang-native vec4

// ---------------------------------------------------------------------------
// Kernel 1: W_dw[b, j] = dot(z[b, :], W_lin[j, :])   j in [0, OUT_C*K*K)
// ---------------------------------------------------------------------------
__global__ void hyper_gemm_kernel(const float* __restrict__ z,
                                  const float* __restrict__ W_lin,
                                  float* __restrict__ wdw) {
    const int tid = blockIdx.x * blockDim.x + threadIdx.x;
    const int total = BATCH * OUT_C * KK * KK;   // 36864
    if (tid >= total) return;
    const int b = tid / (OUT_C * KK * KK);
    const int j = tid - b * (OUT_C * KK * KK);

    const vf4* zr = reinterpret_cast<const vf4*>(z + b * Z_DIM);
    const vf4* wr = reinterpret_cast<const vf4*>(W_lin + (size_t)j * Z_DIM);

    float acc = 0.f;
#pragma unroll
    for (int i = 0; i < Z_DIM / 4; ++i) {
        vf4 a = zr[i];
        vf4 w = wr[i];
        acc += a.x * w.x + a.y * w.y + a.z * w.z + a.w * w.w;
    }
    wdw[tid] = acc;
}

// ---------------------------------------------------------------------------
// Kernel 2: depthwise 3x3 conv, pad 1, per-sample weights.
//
// Grid: 2 blocks per (b,c) plane (64-row slab each), 256 threads:
//   tcol = tid & 31  -> 4 consecutive cols  (32*4 = 128 = W)
//   trow = tid >> 5  -> 8 row-groups x 8 rows = 64-row slab
//
// Per-instruction memory pattern: 64 lanes x dwordx4 = TWO complete
// contiguous 512B rows for every load AND every store (no partial
// cachelines -> no HBM write amplification; round-3 counter evidence:
// interleaved 16B@32B-stride nt stores blew WRITE_SIZE up 1.77x).
//
// Each thread loads its 10 rows (8 out + 2 halo) upfront as raw dwordx4;
// sched_barrier(0) pins all 10 loads BEFORE any consumption so the
// scheduler cannot sink them (round-3 evidence: VGPR=36, loads got
// serialized). Column halos via intra-wave __shfl_up/down — zero
// uncoalesced loads.
// ---------------------------------------------------------------------------
__global__ __launch_bounds__(256)
void dwconv3x3_kernel(const float* __restrict__ x,
                      const float* __restrict__ wdw,
                      float* __restrict__ out) {
    const int slab  = blockIdx.x & 1;          // 0 = rows 0..63, 1 = rows 64..127
    const int plane = blockIdx.x >> 1;         // b*OUT_C + c

    const float* __restrict__ xin  = x   + (size_t)plane * (H_DIM * W_DIM);
    float*       __restrict__ oout = out + (size_t)plane * (H_DIM * W_DIM);

    // 9 per-plane weights — uniform address, scalar (SGPR) loads.
    const float* __restrict__ wp = wdw + (size_t)plane * (KK * KK);
    const float w00 = wp[0], w01 = wp[1], w02 = wp[2];
    const float w10 = wp[3], w11 = wp[4], w12 = wp[5];
    const float w20 = wp[6], w21 = wp[7], w22 = wp[8];

    const int tcol = threadIdx.x & 31;
    const int trow = threadIdx.x >> 5;         // 0..7
    const int c0   = tcol * 4;                 // 0..124
    const int r0   = slab * 64 + trow * 8;     // 0..120

    // ---- phase 1: issue all 10 coalesced row loads, pinned upfront ----
    vf4 raw[10];
#pragma unroll
    for (int i = 0; i < 10; ++i) {
        const int ir  = r0 - 1 + i;                          // r0-1 .. r0+8
        const int irc = ir < 0 ? 0 : (ir > H_DIM - 1 ? H_DIM - 1 : ir);
        raw[i] = *reinterpret_cast<const vf4*>(xin + irc * W_DIM + c0);
    }
    __builtin_amdgcn_sched_barrier(0);   // loads stay above; consumption below

    // ---- phase 2: zero-mask out-of-plane rows + column halos via shuffle ----
    vf4   m[10];
    float lft[10], rgt[10];
#pragma unroll
    for (int i = 0; i < 10; ++i) {
        const int ir = r0 - 1 + i;
        const float msk = (ir >= 0 && ir < H_DIM) ? 1.f : 0.f;   // v_cndmask
        m[i] = raw[i] * msk;
        const float tl = __shfl_up(m[i].w, 1);     // lane-1's col c0-1
        const float tr = __shfl_down(m[i].x, 1);   // lane+1's col c0+4
        lft[i] = (tcol == 0)  ? 0.f : tl;
        rgt[i] = (tcol == 31) ? 0.f : tr;
    }

    // ---- phase 3: 8 output rows, 9 FMA per output, contiguous stores ----
#pragma unroll
    for (int j = 0; j < 8; ++j) {
        const float A[6] = { lft[j],     m[j].x,     m[j].y,     m[j].z,     m[j].w,     rgt[j]     };
        const float B[6] = { lft[j + 1], m[j + 1].x, m[j + 1].y, m[j + 1].z, m[j + 1].w, rgt[j + 1] };
        const float C[6] = { lft[j + 2], m[j + 2].x, m[j + 2].y, m[j + 2].z, m[j + 2].w, rgt[j + 2] };

        vf4 s;
        float o[4];
#pragma unroll
        for (int k = 0; k < 4; ++k) {
            float a;
            a = fmaf(w00, A[k], fmaf(w01, A[k + 1], w02 * A[k + 2]));
            a = fmaf(w10, B[k], fmaf(w11, B[k + 1], fmaf(w12, B[k + 2], a)));
            a = fmaf(w20, C[k], fmaf(w21, C[k + 1], fmaf(w22, C[k + 2], a)));
            o[k] = a;
        }
        s.x = o[0]; s.y = o[1]; s.z = o[2]; s.w = o[3];
        *reinterpret_cast<vf4*>(oout + (r0 + j) * W_DIM + c0) = s;
    }
}

// ---------------------------------------------------------------------------
extern "C" void kernel_launch(void* const* d_in, const int* in_sizes, int n_in,
                              void* d_out, int out_size, void* d_ws, size_t ws_size,
                              hipStream_t stream) {
    const float* x     = (const float*)d_in[0];   // (B, C, H, W)
    const float* z     = (const float*)d_in[1];   // (B, Z)
    const float* W_lin = (const float*)d_in[2];   // (C*K*K, Z)
    float* out = (float*)d_out;
    float* wdw = (float*)d_ws;                    // (B, C*K*K) = 36864 floats

    // Stage 1: hypernetwork weights
    {
        const int total = BATCH * OUT_C * KK * KK;  // 36864
        const int blk = 256;
        hyper_gemm_kernel<<<(total + blk - 1) / blk, blk, 0, stream>>>(z, W_lin, wdw);
    }

    // Stage 2: depthwise conv — two blocks per (b,c) plane
    {
        const int grid = BATCH * OUT_C * 2;         // 8192
        dwconv3x3_kernel<<<grid, 256, 0, stream>>>(x, wdw, out);
    }
}

// Round 6
// 87.015 us; speedup vs baseline: 1.9059x; 1.1740x over previous
//
#include <hip/hip_runtime.h>
#include <hip/hip_bf16.h>

// Problem constants (from reference)
#define BATCH   16
#define OUT_C   256
#define KK      3
#define Z_DIM   64
#define H_DIM   128
#define W_DIM   128

typedef float vf4 __attribute__((ext_vector_type(4)));   // clang-native vec4

// ---------------------------------------------------------------------------
// Kernel 1: W_dw[b, j] = dot(z[b, :], W_lin[j, :])   j in [0, OUT_C*K*K)
// ---------------------------------------------------------------------------
__global__ void hyper_gemm_kernel(const float* __restrict__ z,
                                  const float* __restrict__ W_lin,
                                  float* __restrict__ wdw) {
    const int tid = blockIdx.x * blockDim.x + threadIdx.x;
    const int total = BATCH * OUT_C * KK * KK;   // 36864
    if (tid >= total) return;
    const int b = tid / (OUT_C * KK * KK);
    const int j = tid - b * (OUT_C * KK * KK);

    const vf4* zr = reinterpret_cast<const vf4*>(z + b * Z_DIM);
    const vf4* wr = reinterpret_cast<const vf4*>(W_lin + (size_t)j * Z_DIM);

    float acc = 0.f;
#pragma unroll
    for (int i = 0; i < Z_DIM / 4; ++i) {
        vf4 a = zr[i];
        vf4 w = wr[i];
        acc += a.x * w.x + a.y * w.y + a.z * w.z + a.w * w.w;
    }
    wdw[tid] = acc;
}

// ---------------------------------------------------------------------------
// Kernel 2: depthwise 3x3 conv, pad 1, per-sample weights.
//
// Grid: 2 blocks per (b,c) plane (64-row slab each), 256 threads:
//   tcol = tid & 31  -> 4 consecutive cols  (32*4 = 128 = W)
//   trow = tid >> 5  -> 8 row-groups x 8 rows = 64-row slab
//
// Per-instruction memory pattern: 64 lanes x dwordx4 = TWO complete
// contiguous 512B rows for every load AND every store (no partial
// cachelines -> no HBM write amplification; round-3 counter evidence:
// interleaved 16B@32B-stride nt stores blew WRITE_SIZE up 1.77x).
//
// Each thread loads its 10 rows (8 out + 2 halo) upfront as raw dwordx4;
// sched_barrier(0) pins all 10 loads BEFORE any consumption so the
// scheduler cannot sink them (round-3 evidence: VGPR=36, loads got
// serialized). Column halos via intra-wave __shfl_up/down — zero
// uncoalesced loads.
//
// Round-5 change: output stores are NON-TEMPORAL. out is write-once /
// never-read; streaming it keeps x L3-resident across replays (x = 256 MB
// = exactly L3 size; round-4 FETCH of 162 MB showed the write stream was
// evicting it). Full-line stores mean nt cannot cause write amplification.
// ---------------------------------------------------------------------------
__global__ __launch_bounds__(256)
void dwconv3x3_kernel(const float* __restrict__ x,
                      const float* __restrict__ wdw,
                      float* __restrict__ out) {
    const int slab  = blockIdx.x & 1;          // 0 = rows 0..63, 1 = rows 64..127
    const int plane = blockIdx.x >> 1;         // b*OUT_C + c

    const float* __restrict__ xin  = x   + (size_t)plane * (H_DIM * W_DIM);
    float*       __restrict__ oout = out + (size_t)plane * (H_DIM * W_DIM);

    // 9 per-plane weights — uniform address, scalar (SGPR) loads.
    const float* __restrict__ wp = wdw + (size_t)plane * (KK * KK);
    const float w00 = wp[0], w01 = wp[1], w02 = wp[2];
    const float w10 = wp[3], w11 = wp[4], w12 = wp[5];
    const float w20 = wp[6], w21 = wp[7], w22 = wp[8];

    const int tcol = threadIdx.x & 31;
    const int trow = threadIdx.x >> 5;         // 0..7
    const int c0   = tcol * 4;                 // 0..124
    const int r0   = slab * 64 + trow * 8;     // 0..120

    // ---- phase 1: issue all 10 coalesced row loads, pinned upfront ----
    vf4 raw[10];
#pragma unroll
    for (int i = 0; i < 10; ++i) {
        const int ir  = r0 - 1 + i;                          // r0-1 .. r0+8
        const int irc = ir < 0 ? 0 : (ir > H_DIM - 1 ? H_DIM - 1 : ir);
        raw[i] = *reinterpret_cast<const vf4*>(xin + irc * W_DIM + c0);
    }
    __builtin_amdgcn_sched_barrier(0);   // loads stay above; consumption below

    // ---- phase 2: zero-mask out-of-plane rows + column halos via shuffle ----
    vf4   m[10];
    float lft[10], rgt[10];
#pragma unroll
    for (int i = 0; i < 10; ++i) {
        const int ir = r0 - 1 + i;
        const float msk = (ir >= 0 && ir < H_DIM) ? 1.f : 0.f;   // v_cndmask
        m[i] = raw[i] * msk;
        const float tl = __shfl_up(m[i].w, 1);     // lane-1's col c0-1
        const float tr = __shfl_down(m[i].x, 1);   // lane+1's col c0+4
        lft[i] = (tcol == 0)  ? 0.f : tl;
        rgt[i] = (tcol == 31) ? 0.f : tr;
    }

    // ---- phase 3: 8 output rows, 9 FMA per output, contiguous nt stores ----
#pragma unroll
    for (int j = 0; j < 8; ++j) {
        const float A[6] = { lft[j],     m[j].x,     m[j].y,     m[j].z,     m[j].w,     rgt[j]     };
        const float B[6] = { lft[j + 1], m[j + 1].x, m[j + 1].y, m[j + 1].z, m[j + 1].w, rgt[j + 1] };
        const float C[6] = { lft[j + 2], m[j + 2].x, m[j + 2].y, m[j + 2].z, m[j + 2].w, rgt[j + 2] };

        vf4 s;
        float o[4];
#pragma unroll
        for (int k = 0; k < 4; ++k) {
            float a;
            a = fmaf(w00, A[k], fmaf(w01, A[k + 1], w02 * A[k + 2]));
            a = fmaf(w10, B[k], fmaf(w11, B[k + 1], fmaf(w12, B[k + 2], a)));
            a = fmaf(w20, C[k], fmaf(w21, C[k + 1], fmaf(w22, C[k + 2], a)));
            o[k] = a;
        }
        s.x = o[0]; s.y = o[1]; s.z = o[2]; s.w = o[3];
        __builtin_nontemporal_store(
            s, reinterpret_cast<vf4*>(oout + (r0 + j) * W_DIM + c0));
    }
}

// ---------------------------------------------------------------------------
extern "C" void kernel_launch(void* const* d_in, const int* in_sizes, int n_in,
                              void* d_out, int out_size, void* d_ws, size_t ws_size,
                              hipStream_t stream) {
    const float* x     = (const float*)d_in[0];   // (B, C, H, W)
    const float* z     = (const float*)d_in[1];   // (B, Z)
    const float* W_lin = (const float*)d_in[2];   // (C*K*K, Z)
    float* out = (float*)d_out;
    float* wdw = (float*)d_ws;                    // (B, C*K*K) = 36864 floats

    // Stage 1: hypernetwork weights
    {
        const int total = BATCH * OUT_C * KK * KK;  // 36864
        const int blk = 256;
        hyper_gemm_kernel<<<(total + blk - 1) / blk, blk, 0, stream>>>(z, W_lin, wdw);
    }

    // Stage 2: depthwise conv — two blocks per (b,c) plane
    {
        const int grid = BATCH * OUT_C * 2;         // 8192
        dwconv3x3_kernel<<<grid, 256, 0, stream>>>(x, wdw, out);
    }
}

// Round 7
// 82.507 us; speedup vs baseline: 2.0100x; 1.0546x over previous
//
#include <hip/hip_runtime.h>
#include <hip/hip_bf16.h>

// Problem constants (from reference)
#define BATCH   16
#define OUT_C   256
#define KK      3
#define Z_DIM   64
#define H_DIM   128
#define W_DIM   128

typedef float vf4 __attribute__((ext_vector_type(4)));   // clang-native vec4

// ---------------------------------------------------------------------------
// Fused kernel: hypernetwork weights + depthwise 3x3 conv, pad 1.
//
// Grid: 2 blocks per (b,c) plane (64-row slab each), 256 threads:
//   tcol = tid & 31  -> 4 consecutive cols  (32*4 = 128 = W)
//   trow = tid >> 5  -> 8 row-groups x 8 rows = 64-row slab
//
// Round-4/5 structure kept verbatim (it reached 94% of the copy roofline):
//  - every load/store instruction covers two complete contiguous 512B rows
//    (64 lanes x dwordx4) -> no partial-line HBM write amplification
//  - 10 row-loads issued upfront, pinned with sched_barrier(0) (VGPR
//    evidence from round 3: without it the scheduler sinks + serializes)
//  - column halos via intra-wave __shfl_up/down, zero uncoalesced loads
//  - nt stores: out is write-once/never-read; keeps x L3-resident
//    (round-5 evidence: FETCH 162 -> 134 MB)
//
// Round-6 change: the tiny hypernetwork GEMM is fused in. Each wave computes
// its plane's 9 weights (dot(z[b,:], W_lin[c*9+j,:]), 64-lane shfl_xor
// reduction) WHILE its 10 x-row loads are in flight -- the weight math hides
// entirely under the ~900-cycle HBM latency, and the separate hyper_gemm
// dispatch + graph edge + wdw HBM round-trip disappear. W_lin (590 KB) is
// L2/L3-resident, so extra HBM fetch is negligible.
// ---------------------------------------------------------------------------
__global__ __launch_bounds__(256)
void dwconv3x3_fused_kernel(const float* __restrict__ x,
                            const float* __restrict__ z,
                            const float* __restrict__ W_lin,
                            float* __restrict__ out) {
    const int slab  = blockIdx.x & 1;          // 0 = rows 0..63, 1 = rows 64..127
    const int plane = blockIdx.x >> 1;         // b*OUT_C + c
    const int b     = plane >> 8;              // plane / OUT_C
    const int c     = plane & 255;             // plane % OUT_C

    const float* __restrict__ xin  = x   + (size_t)plane * (H_DIM * W_DIM);
    float*       __restrict__ oout = out + (size_t)plane * (H_DIM * W_DIM);

    const int tcol = threadIdx.x & 31;
    const int trow = threadIdx.x >> 5;         // 0..7
    const int c0   = tcol * 4;                 // 0..124
    const int r0   = slab * 64 + trow * 8;     // 0..120

    // ---- phase 1: issue all 10 coalesced x-row loads, pinned upfront ----
    vf4 raw[10];
#pragma unroll
    for (int i = 0; i < 10; ++i) {
        const int ir  = r0 - 1 + i;                          // r0-1 .. r0+8
        const int irc = ir < 0 ? 0 : (ir > H_DIM - 1 ? H_DIM - 1 : ir);
        raw[i] = *reinterpret_cast<const vf4*>(xin + irc * W_DIM + c0);
    }
    __builtin_amdgcn_sched_barrier(0);   // x loads stay above; rest below

    // ---- phase 1b: hypernetwork weights, hidden under the load latency ----
    // lane l holds z[b,l]; 9 coalesced W_lin rows; full-wave xor reduction.
    const int lane = threadIdx.x & 63;
    const float zv = z[b * Z_DIM + lane];
    float wsum[9];
#pragma unroll
    for (int j = 0; j < 9; ++j) {
        float p = zv * W_lin[(size_t)(c * (KK * KK) + j) * Z_DIM + lane];
#pragma unroll
        for (int off = 32; off; off >>= 1)
            p += __shfl_xor(p, off);
        wsum[j] = p;                      // all lanes hold the dot product
    }
    const float w00 = wsum[0], w01 = wsum[1], w02 = wsum[2];
    const float w10 = wsum[3], w11 = wsum[4], w12 = wsum[5];
    const float w20 = wsum[6], w21 = wsum[7], w22 = wsum[8];

    // ---- phase 2: zero-mask out-of-plane rows + column halos via shuffle ----
    vf4   m[10];
    float lft[10], rgt[10];
#pragma unroll
    for (int i = 0; i < 10; ++i) {
        const int ir = r0 - 1 + i;
        const float msk = (ir >= 0 && ir < H_DIM) ? 1.f : 0.f;   // v_cndmask
        m[i] = raw[i] * msk;
        const float tl = __shfl_up(m[i].w, 1);     // lane-1's col c0-1
        const float tr = __shfl_down(m[i].x, 1);   // lane+1's col c0+4
        lft[i] = (tcol == 0)  ? 0.f : tl;
        rgt[i] = (tcol == 31) ? 0.f : tr;
    }

    // ---- phase 3: 8 output rows, 9 FMA per output, contiguous nt stores ----
#pragma unroll
    for (int j = 0; j < 8; ++j) {
        const float A[6] = { lft[j],     m[j].x,     m[j].y,     m[j].z,     m[j].w,     rgt[j]     };
        const float B[6] = { lft[j + 1], m[j + 1].x, m[j + 1].y, m[j + 1].z, m[j + 1].w, rgt[j + 1] };
        const float C[6] = { lft[j + 2], m[j + 2].x, m[j + 2].y, m[j + 2].z, m[j + 2].w, rgt[j + 2] };

        vf4 s;
        float o[4];
#pragma unroll
        for (int k = 0; k < 4; ++k) {
            float a;
            a = fmaf(w00, A[k], fmaf(w01, A[k + 1], w02 * A[k + 2]));
            a = fmaf(w10, B[k], fmaf(w11, B[k + 1], fmaf(w12, B[k + 2], a)));
            a = fmaf(w20, C[k], fmaf(w21, C[k + 1], fmaf(w22, C[k + 2], a)));
            o[k] = a;
        }
        s.x = o[0]; s.y = o[1]; s.z = o[2]; s.w = o[3];
        __builtin_nontemporal_store(
            s, reinterpret_cast<vf4*>(oout + (r0 + j) * W_DIM + c0));
    }
}

// ---------------------------------------------------------------------------
extern "C" void kernel_launch(void* const* d_in, const int* in_sizes, int n_in,
                              void* d_out, int out_size, void* d_ws, size_t ws_size,
                              hipStream_t stream) {
    const float* x     = (const float*)d_in[0];   // (B, C, H, W)
    const float* z     = (const float*)d_in[1];   // (B, Z)
    const float* W_lin = (const float*)d_in[2];   // (C*K*K, Z)
    float* out = (float*)d_out;

    // Single fused dispatch: weights + depthwise conv
    const int grid = BATCH * OUT_C * 2;           // 8192
    dwconv3x3_fused_kernel<<<grid, 256, 0, stream>>>(x, z, W_lin, out);
}